// Round 1
// baseline (427.836 us; speedup 1.0000x reference)
//
#include <hip/hip_runtime.h>

// GraphSAGE layer: out = relu(x @ W_self^T + b_self + (scatter_mean of x over edges) @ W_neigh^T + b_neigh)
// N=50000 nodes, E=800000 edges, dim 64->64, fp32.

#define N_NODES 50000
#define N_EDGES 800000
#define DIM 64

// ---------------------------------------------------------------------------
// Kernel 1: edge scatter. One 64-lane wave per edge: lane d does
//   agg[src][d] += x[dst][d]   (fp32 global atomic)
// lane 0 additionally counts degree.
// Gather read x[dst*64 + lane] is 256B contiguous per wave -> coalesced;
// x (12.8MB) is L3-resident so repeats hit Infinity Cache.
// ---------------------------------------------------------------------------
__global__ __launch_bounds__(256) void sage_scatter(
    const float* __restrict__ x,
    const int* __restrict__ src,
    const int* __restrict__ dst,
    float* __restrict__ agg,
    float* __restrict__ deg)
{
    int tid = blockIdx.x * blockDim.x + threadIdx.x;
    int e = tid >> 6;
    if (e >= N_EDGES) return;
    int lane = tid & 63;
    int s = src[e];
    int d = dst[e];
    float v = x[d * DIM + lane];
    atomicAdd(&agg[s * DIM + lane], v);
    if (lane == 0) atomicAdd(&deg[s], 1.0f);
}

// ---------------------------------------------------------------------------
// Kernel 2: fused normalize + dual GEMM + bias + relu.
// Block = 256 threads = 4 nodes x 64 output dims.
// W_self/W_neigh transposed into LDS (WT[k][o], lane-indexed by o ->
// consecutive addresses across lanes, 2 lanes/bank = free).
// x and agg rows staged in LDS, read as wave-broadcast (same addr, free).
// ---------------------------------------------------------------------------
__global__ __launch_bounds__(256) void sage_gemm(
    const float* __restrict__ x,
    const float* __restrict__ agg,
    const float* __restrict__ deg,
    const float* __restrict__ Wself,
    const float* __restrict__ bself,
    const float* __restrict__ Wneigh,
    const float* __restrict__ bneigh,
    float* __restrict__ out)
{
    __shared__ float WsT[DIM * DIM];   // WsT[k*64 + o] = Wself[o*64 + k]
    __shared__ float WnT[DIM * DIM];
    __shared__ float xs[4][DIM];
    __shared__ float as[4][DIM];

    int t = threadIdx.x;

    // Load both weight matrices transposed into LDS. One-time cost per block.
    #pragma unroll
    for (int i = 0; i < 16; ++i) {
        int idx = t + i * 256;          // 0..4095
        int o = idx >> 6;
        int k = idx & 63;
        WsT[k * DIM + o] = Wself[idx];
        WnT[k * DIM + o] = Wneigh[idx];
    }

    int ln = t >> 6;                    // local node 0..3
    int o  = t & 63;                    // output dim
    int node = blockIdx.x * 4 + ln;

    if (node < N_NODES) {
        xs[ln][o] = x[node * DIM + o];
        float dg = deg[node];           // wave-uniform broadcast load
        float invdeg = 1.0f / fmaxf(dg, 1.0f);
        as[ln][o] = agg[node * DIM + o] * invdeg;
    }
    __syncthreads();
    if (node >= N_NODES) return;

    float acc = bself[o] + bneigh[o];
    #pragma unroll
    for (int k = 0; k < DIM; ++k) {
        acc = fmaf(xs[ln][k], WsT[k * DIM + o], acc);
        acc = fmaf(as[ln][k], WnT[k * DIM + o], acc);
    }
    out[node * DIM + o] = fmaxf(acc, 0.0f);
}

extern "C" void kernel_launch(void* const* d_in, const int* in_sizes, int n_in,
                              void* d_out, int out_size, void* d_ws, size_t ws_size,
                              hipStream_t stream)
{
    const float* x      = (const float*)d_in[0];
    const int*   ei     = (const int*)d_in[1];   // [2, E]: row 0 = src, row 1 = dst
    const float* Wself  = (const float*)d_in[2];
    const float* bself  = (const float*)d_in[3];
    const float* Wneigh = (const float*)d_in[4];
    const float* bneigh = (const float*)d_in[5];
    float* out = (float*)d_out;

    float* agg = (float*)d_ws;                   // N*64 floats
    float* deg = agg + (size_t)N_NODES * DIM;    // N floats

    size_t zero_bytes = ((size_t)N_NODES * DIM + N_NODES) * sizeof(float);
    hipMemsetAsync(d_ws, 0, zero_bytes, stream);

    // Scatter: one wave per edge.
    {
        long long total = (long long)N_EDGES * 64;
        int blocks = (int)((total + 255) / 256);
        sage_scatter<<<blocks, 256, 0, stream>>>(x, ei, ei + N_EDGES, agg, deg);
    }

    // Fused normalize + GEMM + bias + relu.
    {
        int blocks = (N_NODES + 3) / 4;
        sage_gemm<<<blocks, 256, 0, stream>>>(x, agg, deg, Wself, bself,
                                              Wneigh, bneigh, out);
    }
}

// Round 2
// 205.829 us; speedup vs baseline: 2.0786x; 2.0786x over previous
//
#include <hip/hip_runtime.h>

// GraphSAGE layer, fp32, N=50000 nodes, E=800000 edges, 64->64.
// Pipeline: memset(cnt) -> hist -> scan(reduce/partials/write) -> CSR fill
//           -> gather-mean aggregation (no fp atomics) -> node-per-lane GEMM.

#define N_NODES 50000
#define N_EDGES 800000
#define DIM 64
#define NB_SCAN 49            // 49 blocks * 1024 = 50176 >= N_NODES
#define CNT_PAD (NB_SCAN * 1024)

// ---------------------------------------------------------------------------
// 1) degree histogram (int atomics, cheap)
// ---------------------------------------------------------------------------
__global__ __launch_bounds__(256) void sage_hist(const int* __restrict__ src,
                                                 int* __restrict__ cnt)
{
    int e = blockIdx.x * 256 + threadIdx.x;
    if (e < N_EDGES) atomicAdd(&cnt[src[e]], 1);
}

// ---------------------------------------------------------------------------
// 2a) per-1024-chunk reduction for the hierarchical scan
// ---------------------------------------------------------------------------
__global__ __launch_bounds__(256) void scan_reduce(const int* __restrict__ cnt,
                                                   int* __restrict__ partial)
{
    __shared__ int sdata[256];
    int t = threadIdx.x, b = blockIdx.x;
    int s = 0;
#pragma unroll
    for (int i = 0; i < 4; ++i) s += cnt[b * 1024 + i * 256 + t];
    sdata[t] = s; __syncthreads();
    for (int st = 128; st > 0; st >>= 1) {
        if (t < st) sdata[t] += sdata[t + st];
        __syncthreads();
    }
    if (t == 0) partial[b] = sdata[0];
}

// 2b) exclusive scan of the 49 chunk sums (single wave)
__global__ void scan_partials(int* partial)
{
    int t = threadIdx.x;                  // 64 threads
    int orig = (t < NB_SCAN) ? partial[t] : 0;
    int v = orig;
#pragma unroll
    for (int off = 1; off < 64; off <<= 1) {
        int u = __shfl_up(v, off);
        if (t >= off) v += u;
    }
    if (t < NB_SCAN) partial[t] = v - orig;   // exclusive prefix
}

// 2c) per-chunk exclusive scan + chunk prefix -> row offsets (and cursor copy)
__global__ __launch_bounds__(256) void scan_write(const int* __restrict__ cnt,
                                                  const int* __restrict__ partial,
                                                  int* __restrict__ offs,
                                                  int* __restrict__ cursor)
{
    int t = threadIdx.x, b = blockIdx.x;
    int base = b * 1024 + t * 4;
    const int4 c = *reinterpret_cast<const int4*>(cnt + base);
    int tsum = c.x + c.y + c.z + c.w;
    int lane = t & 63, w = t >> 6;
    int v = tsum;
#pragma unroll
    for (int off = 1; off < 64; off <<= 1) {
        int u = __shfl_up(v, off);
        if (lane >= off) v += u;
    }
    __shared__ int wsum[4];
    if (lane == 63) wsum[w] = v;
    __syncthreads();
    int woff = 0;
    for (int k = 0; k < w; ++k) woff += wsum[k];
    int excl = partial[b] + woff + (v - tsum);
    int4 o; o.x = excl; o.y = o.x + c.x; o.z = o.y + c.y; o.w = o.z + c.z;
    *reinterpret_cast<int4*>(offs + base) = o;
    *reinterpret_cast<int4*>(cursor + base) = o;
    // note: offs[N_NODES] is produced automatically (cnt padded with zeros)
}

// ---------------------------------------------------------------------------
// 3) CSR fill: col[] gets dst indices grouped by src (order within a row is
//    nondeterministic, only perturbs fp sum order -> well within threshold)
// ---------------------------------------------------------------------------
__global__ __launch_bounds__(256) void sage_fill(const int* __restrict__ src,
                                                 const int* __restrict__ dst,
                                                 int* __restrict__ cursor,
                                                 int* __restrict__ col)
{
    int e = blockIdx.x * 256 + threadIdx.x;
    if (e < N_EDGES) {
        int s = src[e];
        int pos = atomicAdd(&cursor[s], 1);
        col[pos] = dst[e];
    }
}

// ---------------------------------------------------------------------------
// 4) gather-mean aggregation: one wave per node, lane d sums x[nbr][d].
//    Neighbor indices made wave-uniform (SGPR) via readfirstlane so the
//    x row read is a single coalesced 256B request.
// ---------------------------------------------------------------------------
__global__ __launch_bounds__(256) void sage_agg(const float* __restrict__ x,
                                                const int* __restrict__ col,
                                                const int* __restrict__ offs,
                                                float* __restrict__ agg)
{
    int wid = (blockIdx.x * 256 + threadIdx.x) >> 6;
    int lane = threadIdx.x & 63;
    if (wid >= N_NODES) return;
    int beg = __builtin_amdgcn_readfirstlane(offs[wid]);
    int end = __builtin_amdgcn_readfirstlane(offs[wid + 1]);
    float s = 0.0f;
    int i = beg;
    for (; i + 4 <= end; i += 4) {
        int d0 = __builtin_amdgcn_readfirstlane(col[i]);
        int d1 = __builtin_amdgcn_readfirstlane(col[i + 1]);
        int d2 = __builtin_amdgcn_readfirstlane(col[i + 2]);
        int d3 = __builtin_amdgcn_readfirstlane(col[i + 3]);
        s += x[d0 * DIM + lane];
        s += x[d1 * DIM + lane];
        s += x[d2 * DIM + lane];
        s += x[d3 * DIM + lane];
    }
    for (; i < end; ++i) {
        int d = __builtin_amdgcn_readfirstlane(col[i]);
        s += x[d * DIM + lane];
    }
    int deg = end - beg;
    float inv = 1.0f / (float)(deg > 0 ? deg : 1);
    agg[(size_t)wid * DIM + lane] = s * inv;
}

// ---------------------------------------------------------------------------
// 5) fused dual GEMM + bias + relu, node-per-lane.
//    Lane owns one node: x row + agg row in 128 VGPRs. Weight reads are
//    wave-uniform -> scalar loads (constant cache) -> SGPR operand in v_fma.
// ---------------------------------------------------------------------------
__global__ __launch_bounds__(256) void sage_out(const float* __restrict__ x,
                                                const float* __restrict__ agg,
                                                const float* __restrict__ Ws,
                                                const float* __restrict__ bs,
                                                const float* __restrict__ Wn,
                                                const float* __restrict__ bn,
                                                float* __restrict__ out)
{
    int n = blockIdx.x * 256 + threadIdx.x;
    if (n >= N_NODES) return;

    float xr[DIM], ar[DIM];
    const float4* xp = reinterpret_cast<const float4*>(x + (size_t)n * DIM);
    const float4* ap = reinterpret_cast<const float4*>(agg + (size_t)n * DIM);
#pragma unroll
    for (int i = 0; i < DIM / 4; ++i) {
        float4 v = xp[i];
        xr[i * 4 + 0] = v.x; xr[i * 4 + 1] = v.y; xr[i * 4 + 2] = v.z; xr[i * 4 + 3] = v.w;
        float4 u = ap[i];
        ar[i * 4 + 0] = u.x; ar[i * 4 + 1] = u.y; ar[i * 4 + 2] = u.z; ar[i * 4 + 3] = u.w;
    }

    for (int o = 0; o < DIM; o += 4) {
        float a0 = bs[o + 0] + bn[o + 0];
        float a1 = bs[o + 1] + bn[o + 1];
        float a2 = bs[o + 2] + bn[o + 2];
        float a3 = bs[o + 3] + bn[o + 3];
        const float* ws0 = Ws + o * DIM;
        const float* wn0 = Wn + o * DIM;
#pragma unroll
        for (int k = 0; k < DIM; ++k) {
            float xv = xr[k], av = ar[k];
            a0 = fmaf(xv, ws0[k],           a0); a0 = fmaf(av, wn0[k],           a0);
            a1 = fmaf(xv, ws0[DIM + k],     a1); a1 = fmaf(av, wn0[DIM + k],     a1);
            a2 = fmaf(xv, ws0[2 * DIM + k], a2); a2 = fmaf(av, wn0[2 * DIM + k], a2);
            a3 = fmaf(xv, ws0[3 * DIM + k], a3); a3 = fmaf(av, wn0[3 * DIM + k], a3);
        }
        float4 r;
        r.x = fmaxf(a0, 0.0f); r.y = fmaxf(a1, 0.0f);
        r.z = fmaxf(a2, 0.0f); r.w = fmaxf(a3, 0.0f);
        *reinterpret_cast<float4*>(out + (size_t)n * DIM + o) = r;
    }
}

extern "C" void kernel_launch(void* const* d_in, const int* in_sizes, int n_in,
                              void* d_out, int out_size, void* d_ws, size_t ws_size,
                              hipStream_t stream)
{
    const float* x      = (const float*)d_in[0];
    const int*   ei     = (const int*)d_in[1];   // [2,E]: row 0 = src, row 1 = dst
    const float* Wself  = (const float*)d_in[2];
    const float* bself  = (const float*)d_in[3];
    const float* Wneigh = (const float*)d_in[4];
    const float* bneigh = (const float*)d_in[5];
    float* out = (float*)d_out;

    // workspace layout (4-byte units)
    float* agg   = (float*)d_ws;                       // 3,200,000 floats
    int* col     = (int*)(agg + (size_t)N_NODES * DIM);// 800,000
    int* cnt     = col + N_EDGES;                      // CNT_PAD (50176)
    int* offs    = cnt + CNT_PAD;                      // CNT_PAD (covers offs[N])
    int* cursor  = offs + CNT_PAD;                     // CNT_PAD
    int* partial = cursor + CNT_PAD;                   // 64

    const int* src = ei;
    const int* dst = ei + N_EDGES;

    hipMemsetAsync(cnt, 0, CNT_PAD * sizeof(int), stream);

    sage_hist   <<<(N_EDGES + 255) / 256, 256, 0, stream>>>(src, cnt);
    scan_reduce <<<NB_SCAN, 256, 0, stream>>>(cnt, partial);
    scan_partials<<<1, 64, 0, stream>>>(partial);
    scan_write  <<<NB_SCAN, 256, 0, stream>>>(cnt, partial, offs, cursor);
    sage_fill   <<<(N_EDGES + 255) / 256, 256, 0, stream>>>(src, dst, cursor, col);

    sage_agg <<<(N_NODES * 64 + 255) / 256, 256, 0, stream>>>(x, col, offs, agg);
    sage_out <<<(N_NODES + 255) / 256, 256, 0, stream>>>(x, agg, Wself, bself,
                                                         Wneigh, bneigh, out);
}

// Round 3
// 170.966 us; speedup vs baseline: 2.5025x; 1.2039x over previous
//
#include <hip/hip_runtime.h>

// GraphSAGE layer, fp32, N=50000 nodes, E=800000 edges, 64->64.
// Pipeline: memset(cnt) -> hist -> scan(reduce/partials/write) -> CSR fill
//           -> gather-mean aggregation (no fp atomics) -> GEMM (node x out-group).

#define N_NODES 50000
#define N_EDGES 800000
#define DIM 64
#define NB_SCAN 49            // 49 blocks * 1024 = 50176 >= N_NODES
#define CNT_PAD (NB_SCAN * 1024)

// ---------------------------------------------------------------------------
// 1) degree histogram (int atomics, cheap)
// ---------------------------------------------------------------------------
__global__ __launch_bounds__(256) void sage_hist(const int* __restrict__ src,
                                                 int* __restrict__ cnt)
{
    int e = blockIdx.x * 256 + threadIdx.x;
    if (e < N_EDGES) atomicAdd(&cnt[src[e]], 1);
}

// ---------------------------------------------------------------------------
// 2a) per-1024-chunk reduction for the hierarchical scan
// ---------------------------------------------------------------------------
__global__ __launch_bounds__(256) void scan_reduce(const int* __restrict__ cnt,
                                                   int* __restrict__ partial)
{
    __shared__ int sdata[256];
    int t = threadIdx.x, b = blockIdx.x;
    int s = 0;
#pragma unroll
    for (int i = 0; i < 4; ++i) s += cnt[b * 1024 + i * 256 + t];
    sdata[t] = s; __syncthreads();
    for (int st = 128; st > 0; st >>= 1) {
        if (t < st) sdata[t] += sdata[t + st];
        __syncthreads();
    }
    if (t == 0) partial[b] = sdata[0];
}

// 2b) exclusive scan of the 49 chunk sums (single wave)
__global__ void scan_partials(int* partial)
{
    int t = threadIdx.x;                  // 64 threads
    int orig = (t < NB_SCAN) ? partial[t] : 0;
    int v = orig;
#pragma unroll
    for (int off = 1; off < 64; off <<= 1) {
        int u = __shfl_up(v, off);
        if (t >= off) v += u;
    }
    if (t < NB_SCAN) partial[t] = v - orig;   // exclusive prefix
}

// 2c) per-chunk exclusive scan + chunk prefix -> row offsets (and cursor copy)
__global__ __launch_bounds__(256) void scan_write(const int* __restrict__ cnt,
                                                  const int* __restrict__ partial,
                                                  int* __restrict__ offs,
                                                  int* __restrict__ cursor)
{
    int t = threadIdx.x, b = blockIdx.x;
    int base = b * 1024 + t * 4;
    const int4 c = *reinterpret_cast<const int4*>(cnt + base);
    int tsum = c.x + c.y + c.z + c.w;
    int lane = t & 63, w = t >> 6;
    int v = tsum;
#pragma unroll
    for (int off = 1; off < 64; off <<= 1) {
        int u = __shfl_up(v, off);
        if (lane >= off) v += u;
    }
    __shared__ int wsum[4];
    if (lane == 63) wsum[w] = v;
    __syncthreads();
    int woff = 0;
    for (int k = 0; k < w; ++k) woff += wsum[k];
    int excl = partial[b] + woff + (v - tsum);
    int4 o; o.x = excl; o.y = o.x + c.x; o.z = o.y + c.y; o.w = o.z + c.z;
    *reinterpret_cast<int4*>(offs + base) = o;
    *reinterpret_cast<int4*>(cursor + base) = o;
}

// ---------------------------------------------------------------------------
// 3) CSR fill
// ---------------------------------------------------------------------------
__global__ __launch_bounds__(256) void sage_fill(const int* __restrict__ src,
                                                 const int* __restrict__ dst,
                                                 int* __restrict__ cursor,
                                                 int* __restrict__ col)
{
    int e = blockIdx.x * 256 + threadIdx.x;
    if (e < N_EDGES) {
        int s = src[e];
        int pos = atomicAdd(&cursor[s], 1);
        col[pos] = dst[e];
    }
}

// ---------------------------------------------------------------------------
// 4) gather-mean aggregation: one wave per node, lane d sums x[nbr][d].
//    col[] reads are wave-uniform (SGPR index chain from readfirstlane) ->
//    scalar loads; 8 independent x-row gathers in flight per iteration.
// ---------------------------------------------------------------------------
__global__ __launch_bounds__(256) void sage_agg(const float* __restrict__ x,
                                                const int* __restrict__ col,
                                                const int* __restrict__ offs,
                                                float* __restrict__ agg)
{
    int wid = (blockIdx.x * 256 + threadIdx.x) >> 6;
    int lane = threadIdx.x & 63;
    if (wid >= N_NODES) return;
    int beg = __builtin_amdgcn_readfirstlane(offs[wid]);
    int end = __builtin_amdgcn_readfirstlane(offs[wid + 1]);
    float s = 0.0f;
    int i = beg;
    for (; i + 8 <= end; i += 8) {
        int d0 = __builtin_amdgcn_readfirstlane(col[i + 0]);
        int d1 = __builtin_amdgcn_readfirstlane(col[i + 1]);
        int d2 = __builtin_amdgcn_readfirstlane(col[i + 2]);
        int d3 = __builtin_amdgcn_readfirstlane(col[i + 3]);
        int d4 = __builtin_amdgcn_readfirstlane(col[i + 4]);
        int d5 = __builtin_amdgcn_readfirstlane(col[i + 5]);
        int d6 = __builtin_amdgcn_readfirstlane(col[i + 6]);
        int d7 = __builtin_amdgcn_readfirstlane(col[i + 7]);
        float s0 = x[d0 * DIM + lane] + x[d1 * DIM + lane];
        float s1 = x[d2 * DIM + lane] + x[d3 * DIM + lane];
        float s2 = x[d4 * DIM + lane] + x[d5 * DIM + lane];
        float s3 = x[d6 * DIM + lane] + x[d7 * DIM + lane];
        s += (s0 + s1) + (s2 + s3);
    }
    for (; i < end; ++i) {
        int d = __builtin_amdgcn_readfirstlane(col[i]);
        s += x[d * DIM + lane];
    }
    int deg = end - beg;
    float inv = 1.0f / (float)(deg > 0 ? deg : 1);
    agg[(size_t)wid * DIM + lane] = s * inv;
}

// ---------------------------------------------------------------------------
// 5) fused dual GEMM + bias + relu.
//    Thread = (node, 16-output group). Wave = 64 consecutive nodes, one
//    output group (wave-uniform) -> all weight/bias reads are scalar loads.
//    k processed in float4 chunks: live state = 16 acc + 8 inputs, no
//    per-thread arrays spanning loops -> no scratch spills.
//    Grid = 782 blocks * 4 waves = 3128 waves (~12 waves/CU).
// ---------------------------------------------------------------------------
__global__ __launch_bounds__(256) void sage_out(const float* __restrict__ x,
                                                const float* __restrict__ agg,
                                                const float* __restrict__ Ws,
                                                const float* __restrict__ bs,
                                                const float* __restrict__ Wn,
                                                const float* __restrict__ bn,
                                                float* __restrict__ out)
{
    int wave = blockIdx.x * 4 + (threadIdx.x >> 6);   // 0 .. 3127
    int lane = threadIdx.x & 63;
    int ng = wave >> 2;                               // node group 0..781
    int og = __builtin_amdgcn_readfirstlane(wave & 3);// output group, SGPR
    int node = ng * 64 + lane;
    if (node >= N_NODES) return;

    const int obase = og * 16;
    const float* __restrict__ xrow = x + (size_t)node * DIM;
    const float* __restrict__ arow = agg + (size_t)node * DIM;

    float acc[16];
#pragma unroll
    for (int o = 0; o < 16; ++o) acc[o] = bs[obase + o] + bn[obase + o];

#pragma unroll 2
    for (int kc = 0; kc < DIM; kc += 4) {             // 16 iterations
        float4 xv = *reinterpret_cast<const float4*>(xrow + kc);
        float4 av = *reinterpret_cast<const float4*>(arow + kc);
#pragma unroll
        for (int o = 0; o < 16; ++o) {
            const float* wsp = Ws + (size_t)(obase + o) * DIM + kc;
            const float* wnp = Wn + (size_t)(obase + o) * DIM + kc;
            float a = acc[o];
            a = fmaf(xv.x, wsp[0], a);
            a = fmaf(xv.y, wsp[1], a);
            a = fmaf(xv.z, wsp[2], a);
            a = fmaf(xv.w, wsp[3], a);
            a = fmaf(av.x, wnp[0], a);
            a = fmaf(av.y, wnp[1], a);
            a = fmaf(av.z, wnp[2], a);
            a = fmaf(av.w, wnp[3], a);
            acc[o] = a;
        }
    }

#pragma unroll
    for (int i = 0; i < 4; ++i) {
        float4 r;
        r.x = fmaxf(acc[i * 4 + 0], 0.0f);
        r.y = fmaxf(acc[i * 4 + 1], 0.0f);
        r.z = fmaxf(acc[i * 4 + 2], 0.0f);
        r.w = fmaxf(acc[i * 4 + 3], 0.0f);
        *reinterpret_cast<float4*>(out + (size_t)node * DIM + obase + i * 4) = r;
    }
}

extern "C" void kernel_launch(void* const* d_in, const int* in_sizes, int n_in,
                              void* d_out, int out_size, void* d_ws, size_t ws_size,
                              hipStream_t stream)
{
    const float* x      = (const float*)d_in[0];
    const int*   ei     = (const int*)d_in[1];   // [2,E]: row 0 = src, row 1 = dst
    const float* Wself  = (const float*)d_in[2];
    const float* bself  = (const float*)d_in[3];
    const float* Wneigh = (const float*)d_in[4];
    const float* bneigh = (const float*)d_in[5];
    float* out = (float*)d_out;

    // workspace layout (4-byte units)
    float* agg   = (float*)d_ws;                        // 3,200,000 floats
    int* col     = (int*)(agg + (size_t)N_NODES * DIM); // 800,000
    int* cnt     = col + N_EDGES;                       // CNT_PAD
    int* offs    = cnt + CNT_PAD;                       // CNT_PAD
    int* cursor  = offs + CNT_PAD;                      // CNT_PAD
    int* partial = cursor + CNT_PAD;                    // 64

    const int* src = ei;
    const int* dst = ei + N_EDGES;

    hipMemsetAsync(cnt, 0, CNT_PAD * sizeof(int), stream);

    sage_hist    <<<(N_EDGES + 255) / 256, 256, 0, stream>>>(src, cnt);
    scan_reduce  <<<NB_SCAN, 256, 0, stream>>>(cnt, partial);
    scan_partials<<<1, 64, 0, stream>>>(partial);
    scan_write   <<<NB_SCAN, 256, 0, stream>>>(cnt, partial, offs, cursor);
    sage_fill    <<<(N_EDGES + 255) / 256, 256, 0, stream>>>(src, dst, cursor, col);

    sage_agg <<<(N_NODES * 64 + 255) / 256, 256, 0, stream>>>(x, col, offs, agg);
    sage_out <<<(N_NODES / 64 + 1), 256, 0, stream>>>(x, agg, Wself, bself,
                                                      Wneigh, bneigh, out);
}